// Round 5
// baseline (253.758 us; speedup 1.0000x reference)
//
#include <hip/hip_runtime.h>
#include <hip/hip_bf16.h>

#define NBATCH 32
#define NG 1024
#define DM 256
#define HB 16   // batches per attn pass (ws budget: 2 x 32 MiB)

typedef short bf16x8 __attribute__((ext_vector_type(8)));
typedef float f32x4 __attribute__((ext_vector_type(4)));
typedef unsigned short u16x4 __attribute__((ext_vector_type(4)));
typedef unsigned short u16x8 __attribute__((ext_vector_type(8)));

static __device__ __forceinline__ unsigned short f2bf(float f) {
    __hip_bfloat16 h = __float2bfloat16(f);
    return *reinterpret_cast<unsigned short*>(&h);
}

// async global->LDS, 16B per lane. LDS dest must be wave-uniform (HW adds lane*16).
static __device__ __forceinline__ void gload16(const void* g, void* l) {
    __builtin_amdgcn_global_load_lds(
        (const __attribute__((address_space(1))) unsigned int*)g,
        (__attribute__((address_space(3))) unsigned int*)l, 16, 0, 0);
}

// pack 8 consecutive f32 into a bf16x8 fragment (compiler emits v_cvt_pk_bf16_f32)
static __device__ __forceinline__ bf16x8 pack8(const float* p) {
    float4 a = *(const float4*)p;
    float4 b = *(const float4*)(p + 4);
    union { u16x8 u; bf16x8 h; } t;
    t.u = (u16x8){ f2bf(a.x), f2bf(a.y), f2bf(a.z), f2bf(a.w),
                   f2bf(b.x), f2bf(b.y), f2bf(b.z), f2bf(b.w) };
    return t.h;
}

// ---------------------------------------------------------------------------
// Kernel W: pack Wq|Wk|Wv (f32 [e][d], row e = output col, d = k) -> bf16
// Wb[3][256][256]. 384 KB, L2-resident for proj.
// ---------------------------------------------------------------------------
__global__ __launch_bounds__(256) void wpack_kernel(
    const float* __restrict__ Wq, const float* __restrict__ Wk,
    const float* __restrict__ Wv, unsigned short* __restrict__ Wb)
{
    const int i4 = (blockIdx.x * 256 + threadIdx.x) * 4;   // 0..196604, grid 192
    const int t = i4 >> 16;                                 // 0..2
    const int off = i4 & 65535;
    const float* src = (t == 0) ? Wq : (t == 1) ? Wk : Wv;
    float4 v = *(const float4*)(src + off);
    *(u16x4*)(Wb + i4) = (u16x4){ f2bf(v.x), f2bf(v.y), f2bf(v.z), f2bf(v.w) };
}

// ---------------------------------------------------------------------------
// Kernel A: q/k/v projections, v3 — no LDS, no barriers.
// grid: 1024 = b(32) x rt(32 row-tiles of 32); 4 waves, wave w owns cols
// [w*64, w*64+64); acc[2][4]. A-fragments packed in-reg from global f32 X;
// B-fragments are direct b128 loads from L2-resident bf16 Wb.
// sigq -> d_out (f32); Pt bf16 [b][512][1024] (row 2d = exp(k)*v, 2d+1 = exp(k)).
// ---------------------------------------------------------------------------
__global__ __launch_bounds__(256) void proj_kernel(
    const float* __restrict__ query, const float* __restrict__ key_,
    const float* __restrict__ value,
    const unsigned short* __restrict__ Wb,
    const float* __restrict__ bq, const float* __restrict__ bk,
    const float* __restrict__ bv,
    float* __restrict__ sigq, unsigned short* __restrict__ Pt)
{
    const int bid = blockIdx.x;
    const int b = bid >> 5, rt = bid & 31;
    const int tid = threadIdx.x;
    const int w = tid >> 6, lane = tid & 63;
    const int l15 = lane & 15, lhi = lane >> 4;

    const size_t xbase = ((size_t)b * NG + rt * 32) * DM;

    auto GEMMX = [&](const float* __restrict__ X, const unsigned short* __restrict__ Wf,
                     f32x4 (&acc)[2][4]) {
        #pragma unroll
        for (int mi = 0; mi < 2; ++mi)
            #pragma unroll
            for (int ni = 0; ni < 4; ++ni)
                acc[mi][ni] = (f32x4){0.f, 0.f, 0.f, 0.f};
        #pragma unroll
        for (int kk = 0; kk < 8; ++kk) {
            bf16x8 af[2], bfr[4];
            #pragma unroll
            for (int mi = 0; mi < 2; ++mi)
                af[mi] = pack8(X + xbase + (size_t)(mi * 16 + l15) * DM + kk * 32 + lhi * 8);
            #pragma unroll
            for (int ni = 0; ni < 4; ++ni)
                bfr[ni] = *(const bf16x8*)&Wf[((w * 64 + ni * 16 + l15) << 8) + kk * 32 + lhi * 8];
            #pragma unroll
            for (int mi = 0; mi < 2; ++mi)
                #pragma unroll
                for (int ni = 0; ni < 4; ++ni)
                    acc[mi][ni] = __builtin_amdgcn_mfma_f32_16x16x32_bf16(
                        af[mi], bfr[ni], acc[mi][ni], 0, 0, 0);
        }
    };

    // ---- q ----
    f32x4 aq[2][4];
    GEMMX(query, Wb, aq);
    #pragma unroll
    for (int ni = 0; ni < 4; ++ni) {
        const int colg = w * 64 + ni * 16 + l15;
        const float bqs = bq[colg];
        #pragma unroll
        for (int mi = 0; mi < 2; ++mi)
            #pragma unroll
            for (int r = 0; r < 4; ++r) {
                const int rowg = rt * 32 + mi * 16 + lhi * 4 + r;
                const float qv = aq[mi][ni][r] + bqs;
                sigq[((size_t)b * NG + rowg) * DM + colg] = 1.0f / (1.0f + __expf(-qv));
            }
    }

    // ---- k, v ----
    f32x4 ak[2][4], av[2][4];
    GEMMX(key_,  Wb + 65536,  ak);
    GEMMX(value, Wb + 131072, av);

    #pragma unroll
    for (int ni = 0; ni < 4; ++ni) {
        const int colg = w * 64 + ni * 16 + l15;
        const float bks = bk[colg], bvs = bv[colg];
        #pragma unroll
        for (int mi = 0; mi < 2; ++mi) {
            unsigned short p1[4], p2[4];
            #pragma unroll
            for (int r = 0; r < 4; ++r) {
                const float ek = __expf(ak[mi][ni][r] + bks);
                const float vv = av[mi][ni][r] + bvs;
                p1[r] = f2bf(ek * vv);
                p2[r] = f2bf(ek);
            }
            const int kk0 = rt * 32 + mi * 16 + lhi * 4;
            *(u16x4*)&Pt[((size_t)b * 512 + 2 * colg    ) * NG + kk0] =
                (u16x4){p1[0], p1[1], p1[2], p1[3]};
            *(u16x4*)&Pt[((size_t)b * 512 + 2 * colg + 1) * NG + kk0] =
                (u16x4){p2[0], p2[1], p2[2], p2[3]};
        }
    }
}

// ---------------------------------------------------------------------------
// Kernel B: exp_A = bf16(exp2(sc * dist)) for HB batches. Memory-bound.
// ---------------------------------------------------------------------------
__global__ __launch_bounds__(256) void exp_kernel(
    const float* __restrict__ dist, unsigned short* __restrict__ ea,
    const float* __restrict__ alpha_raw)
{
    const float alpha = log1pf(__expf(alpha_raw[0])) + 1e-6f;
    const float sc = -alpha * 10.0f * 1.44269504088896f;
    const size_t i8 = ((size_t)blockIdx.x * 256 + threadIdx.x) * 8;
    float4 v0 = *(const float4*)(dist + i8);
    float4 v1 = *(const float4*)(dist + i8 + 4);
    u16x8 o = { f2bf(exp2f(sc * v0.x)), f2bf(exp2f(sc * v0.y)),
                f2bf(exp2f(sc * v0.z)), f2bf(exp2f(sc * v0.w)),
                f2bf(exp2f(sc * v1.x)), f2bf(exp2f(sc * v1.y)),
                f2bf(exp2f(sc * v1.z)), f2bf(exp2f(sc * v1.w)) };
    *(u16x8*)(ea + i8) = o;
}

// ---------------------------------------------------------------------------
// Kernel C: pure bf16 GEMM, out = sigq * (num/den). (unchanged from round 3)
// ---------------------------------------------------------------------------
__global__ __launch_bounds__(256) void attn_kernel(
    const unsigned short* __restrict__ ea,
    const unsigned short* __restrict__ Pt,
    float* __restrict__ out)
{
    __shared__ __align__(128) unsigned short lds[2][2][128 * 64];

    const int bid = blockIdx.x;
    const int l = (bid & 7) * 64 + (bid >> 3);   // XCD-chunked, bijective (512%8==0)
    const int b = l >> 5;          // 0..15
    const int m = (l >> 2) & 7;
    const int n = l & 3;

    const int tid = threadIdx.x;
    const int w = tid >> 6, lane = tid & 63;
    const int wm = w >> 1, wn = w & 1;
    const int l15 = lane & 15, lhi = lane >> 4;
    const int lr = lane >> 3, cb = lane & 7;
    const int cbs = cb ^ lr;       // inverse-swizzled source colblock (XOR involution)

    const char* Abase = (const char*)(ea + ((size_t)b * NG + m * 128) * NG);
    const char* Bbase = (const char*)(Pt + ((size_t)b * 512 + n * 128) * NG);

    f32x4 acc[4][4];
    #pragma unroll
    for (int mi = 0; mi < 4; ++mi)
        #pragma unroll
        for (int ni = 0; ni < 4; ++ni)
            acc[mi][ni] = (f32x4){0.f, 0.f, 0.f, 0.f};

    auto STAGE = [&](int buf, int t) {
        #pragma unroll
        for (int i = 0; i < 4; ++i) {
            const int r = w * 32 + i * 8 + lr;          // tile row; r&7 == lr
            const size_t goff = (size_t)r * 2048 + t * 128 + cbs * 16;
            char* ldst = (char*)&lds[buf][0][0] + w * 4096 + i * 1024;
            gload16(Abase + goff, ldst);
            gload16(Bbase + goff, ldst + 16384);
        }
    };

    STAGE(0, 0);
    __syncthreads();

    int cur = 0;
    for (int t = 0; t < 16; ++t) {
        if (t < 15) STAGE(cur ^ 1, t + 1);
        const char* Ab = (const char*)&lds[cur][0][0];
        const char* Bb = (const char*)&lds[cur][1][0];
        #pragma unroll
        for (int kk = 0; kk < 2; ++kk) {
            const int bc = kk * 64 + lhi * 16;          // byte col within row
            bf16x8 af[4], bfr[4];
            #pragma unroll
            for (int mi = 0; mi < 4; ++mi) {
                const int tr = wm * 64 + mi * 16 + l15; // tr&7 == l15&7
                af[mi] = *(const bf16x8*)(Ab + ((tr * 128 + bc) ^ ((tr & 7) << 4)));
            }
            #pragma unroll
            for (int ni = 0; ni < 4; ++ni) {
                const int tr = wn * 64 + ni * 16 + l15;
                bfr[ni] = *(const bf16x8*)(Bb + ((tr * 128 + bc) ^ ((tr & 7) << 4)));
            }
            #pragma unroll
            for (int mi = 0; mi < 4; ++mi)
                #pragma unroll
                for (int ni = 0; ni < 4; ++ni)
                    acc[mi][ni] = __builtin_amdgcn_mfma_f32_16x16x32_bf16(
                        af[mi], bfr[ni], acc[mi][ni], 0, 0, 0);
        }
        __syncthreads();
        cur ^= 1;
    }

    const int parity = lane & 1;
    #pragma unroll
    for (int mi = 0; mi < 4; ++mi)
        #pragma unroll
        for (int ni = 0; ni < 4; ++ni)
            #pragma unroll
            for (int r = 0; r < 4; ++r) {
                const float own = acc[mi][ni][r];
                const float other = __shfl_xor(own, 1, 64);
                if (!parity) {
                    const int colg = n * 128 + wn * 64 + ni * 16 + l15;  // even
                    const int d = colg >> 1;
                    const int rowg = m * 128 + wm * 64 + mi * 16 + lhi * 4 + r;
                    const size_t idx = ((size_t)b * NG + rowg) * DM + d;
                    out[idx] = out[idx] * (own / (other + 1e-8f));  // out holds sigq
                }
            }
}

extern "C" void kernel_launch(void* const* d_in, const int* in_sizes, int n_in,
                              void* d_out, int out_size, void* d_ws, size_t ws_size,
                              hipStream_t stream) {
    const float* query = (const float*)d_in[0];
    const float* key_  = (const float*)d_in[1];
    const float* value = (const float*)d_in[2];
    const float* dist  = (const float*)d_in[3];
    const float* Wq = (const float*)d_in[4];
    const float* bq = (const float*)d_in[5];
    const float* Wk = (const float*)d_in[6];
    const float* bk = (const float*)d_in[7];
    const float* Wv = (const float*)d_in[8];
    const float* bv = (const float*)d_in[9];
    const float* alpha_raw = (const float*)d_in[10];
    float* out = (float*)d_out;

    // ws: Pt bf16 [32][512][1024] (32 MiB) | exp_A bf16 [HB][1024][1024] (32 MiB)
    //     | Wb bf16 [3][256][256] (384 KiB)
    unsigned short* Pt = (unsigned short*)d_ws;
    unsigned short* exp_buf =
        (unsigned short*)((char*)d_ws + (size_t)NBATCH * 512 * NG * sizeof(unsigned short));
    unsigned short* Wb = exp_buf + (size_t)HB * NG * NG;

    wpack_kernel<<<dim3(192), dim3(256), 0, stream>>>(Wq, Wk, Wv, Wb);

    // sigmoid(q) is staged in d_out; proj fully rewrites it every call.
    proj_kernel<<<dim3(1024), dim3(256), 0, stream>>>(
        query, key_, value, Wb, bq, bk, bv, out, Pt);

    for (int h = 0; h < 2; ++h) {
        exp_kernel<<<dim3(8192), dim3(256), 0, stream>>>(
            dist + (size_t)h * HB * NG * NG, exp_buf, alpha_raw);
        attn_kernel<<<dim3(512), dim3(256), 0, stream>>>(
            exp_buf, Pt + (size_t)h * HB * 512 * NG, out + (size_t)h * HB * NG * DM);
    }
}

// Round 6
// 249.797 us; speedup vs baseline: 1.0159x; 1.0159x over previous
//
#include <hip/hip_runtime.h>
#include <hip/hip_bf16.h>

#define NBATCH 32
#define NG 1024
#define DM 256
#define HB 16   // batches per attn pass (ws budget: 2 x 32 MiB)

typedef short bf16x8 __attribute__((ext_vector_type(8)));
typedef float f32x4 __attribute__((ext_vector_type(4)));
typedef unsigned short u16x4 __attribute__((ext_vector_type(4)));
typedef unsigned short u16x8 __attribute__((ext_vector_type(8)));

static __device__ __forceinline__ unsigned short f2bf(float f) {
    __hip_bfloat16 h = __float2bfloat16(f);
    return *reinterpret_cast<unsigned short*>(&h);
}

// async global->LDS, 16B per lane. LDS dest must be wave-uniform (HW adds lane*16).
static __device__ __forceinline__ void gload16(const void* g, void* l) {
    __builtin_amdgcn_global_load_lds(
        (const __attribute__((address_space(1))) unsigned int*)g,
        (__attribute__((address_space(3))) unsigned int*)l, 16, 0, 0);
}

// ---------------------------------------------------------------------------
// Kernel W: pack Wq|Wk|Wv (f32 [e][d]) -> bf16 Wb[3][256][256]. L2-resident.
// ---------------------------------------------------------------------------
__global__ __launch_bounds__(256) void wpack_kernel(
    const float* __restrict__ Wq, const float* __restrict__ Wk,
    const float* __restrict__ Wv, unsigned short* __restrict__ Wb)
{
    const int i4 = (blockIdx.x * 256 + threadIdx.x) * 4;   // grid 192
    const int t = i4 >> 16;                                 // 0..2
    const int off = i4 & 65535;
    const float* src = (t == 0) ? Wq : (t == 1) ? Wk : Wv;
    float4 v = *(const float4*)(src + off);
    *(u16x4*)(Wb + i4) = (u16x4){ f2bf(v.x), f2bf(v.y), f2bf(v.z), f2bf(v.w) };
}

// ---------------------------------------------------------------------------
// Kernel A: q/k/v projections, v4.
// grid: 2048 = b(32) x kt(16 row-tiles of 64) x dt(4 col-tiles of 64),
// XCD-chunk swizzled so the 4 dt-siblings (same X tile) share an XCD's L2.
// Block: 64 rows x 64 cols x 3 matrices; 4 waves, wave owns 16 rows.
// Flat 12-step pipeline (3 matrices x 4 ksteps), double-buffered LDS A tile
// ([64][72] bf16), W fragments direct from L2-resident bf16 Wb.
// sigq -> d_out (f32); Pt bf16 [b][512][1024] (row 2d = exp(k)*v, 2d+1 = exp(k)).
// ---------------------------------------------------------------------------
__global__ __launch_bounds__(256) void proj_kernel(
    const float* __restrict__ query, const float* __restrict__ key_,
    const float* __restrict__ value,
    const unsigned short* __restrict__ Wb,
    const float* __restrict__ bq, const float* __restrict__ bk,
    const float* __restrict__ bv,
    float* __restrict__ sigq, unsigned short* __restrict__ Pt)
{
    __shared__ unsigned short lds[2][64 * 72];

    const int bid = blockIdx.x;
    const int l = (bid & 7) * 256 + (bid >> 3);  // bijective (2048 % 8 == 0)
    const int b = l >> 6, kt = (l >> 2) & 15, dt = l & 3;
    const int tid = threadIdx.x;
    const int w = tid >> 6, lane = tid & 63;
    const int l15 = lane & 15, lhi = lane >> 4;

    const int sr = tid >> 2;             // stage row 0..63
    const int scc = (tid & 3) << 4;      // stage col chunk (16 f32)

    const size_t xbase = ((size_t)b * NG + kt * 64) * DM;
    const float* Xs[3] = { query + xbase, key_ + xbase, value + xbase };

    // stage 64x64 f32 -> bf16 LDS tile for kstep ks
    auto STAGE = [&](int buf, const float* X, int ks) {
        const float* src = X + (size_t)sr * DM + ks * 64 + scc;
        float4 t0 = *(const float4*)(src);
        float4 t1 = *(const float4*)(src + 4);
        float4 t2 = *(const float4*)(src + 8);
        float4 t3 = *(const float4*)(src + 12);
        unsigned short* dst = &lds[buf][sr * 72 + scc];
        *(u16x4*)(dst)      = (u16x4){ f2bf(t0.x), f2bf(t0.y), f2bf(t0.z), f2bf(t0.w) };
        *(u16x4*)(dst + 4)  = (u16x4){ f2bf(t1.x), f2bf(t1.y), f2bf(t1.z), f2bf(t1.w) };
        *(u16x4*)(dst + 8)  = (u16x4){ f2bf(t2.x), f2bf(t2.y), f2bf(t2.z), f2bf(t2.w) };
        *(u16x4*)(dst + 12) = (u16x4){ f2bf(t3.x), f2bf(t3.y), f2bf(t3.z), f2bf(t3.w) };
    };

    f32x4 accs[3][4];
    #pragma unroll
    for (int m = 0; m < 3; ++m)
        #pragma unroll
        for (int ni = 0; ni < 4; ++ni)
            accs[m][ni] = (f32x4){0.f, 0.f, 0.f, 0.f};

    STAGE(0, Xs[0], 0);
    __syncthreads();

    // 12 steps: s = matrix(s>>2) * 4 + kstep(s&3); buffer = s&1
    #pragma unroll
    for (int s = 0; s < 12; ++s) {
        if (s < 11) STAGE((s + 1) & 1, Xs[(s + 1) >> 2], (s + 1) & 3);
        const unsigned short* Wm = Wb + ((s >> 2) << 16);
        const int ks = s & 3;
        #pragma unroll
        for (int kk = 0; kk < 2; ++kk) {
            const int kb = kk * 32 + lhi * 8;
            bf16x8 af = *(const bf16x8*)&lds[s & 1][(w * 16 + l15) * 72 + kb];
            #pragma unroll
            for (int ni = 0; ni < 4; ++ni) {
                bf16x8 bfr = *(const bf16x8*)&Wm[((dt * 64 + ni * 16 + l15) << 8) + ks * 64 + kb];
                accs[s >> 2][ni] = __builtin_amdgcn_mfma_f32_16x16x32_bf16(
                    af, bfr, accs[s >> 2][ni], 0, 0, 0);
            }
        }
        __syncthreads();
    }

    // ---- epilogue: sigq ----
    #pragma unroll
    for (int ni = 0; ni < 4; ++ni) {
        const int colg = dt * 64 + ni * 16 + l15;
        const float bqs = bq[colg];
        #pragma unroll
        for (int r = 0; r < 4; ++r) {
            const int rowg = kt * 64 + w * 16 + lhi * 4 + r;
            const float qv = accs[0][ni][r] + bqs;
            sigq[((size_t)b * NG + rowg) * DM + colg] = 1.0f / (1.0f + __expf(-qv));
        }
    }

    // ---- epilogue: Pt (num/den interleaved, B^T layout) ----
    #pragma unroll
    for (int ni = 0; ni < 4; ++ni) {
        const int colg = dt * 64 + ni * 16 + l15;
        const float bks = bk[colg], bvs = bv[colg];
        unsigned short p1[4], p2[4];
        #pragma unroll
        for (int r = 0; r < 4; ++r) {
            const float ek = __expf(accs[1][ni][r] + bks);
            const float vv = accs[2][ni][r] + bvs;
            p1[r] = f2bf(ek * vv);
            p2[r] = f2bf(ek);
        }
        const int kk0 = kt * 64 + w * 16 + lhi * 4;
        *(u16x4*)&Pt[((size_t)b * 512 + 2 * colg    ) * NG + kk0] =
            (u16x4){p1[0], p1[1], p1[2], p1[3]};
        *(u16x4*)&Pt[((size_t)b * 512 + 2 * colg + 1) * NG + kk0] =
            (u16x4){p2[0], p2[1], p2[2], p2[3]};
    }
}

// ---------------------------------------------------------------------------
// Kernel B: exp_A = bf16(exp2(sc * dist)) for HB batches. Memory-bound.
// ---------------------------------------------------------------------------
__global__ __launch_bounds__(256) void exp_kernel(
    const float* __restrict__ dist, unsigned short* __restrict__ ea,
    const float* __restrict__ alpha_raw)
{
    const float alpha = log1pf(__expf(alpha_raw[0])) + 1e-6f;
    const float sc = -alpha * 10.0f * 1.44269504088896f;
    const size_t i8 = ((size_t)blockIdx.x * 256 + threadIdx.x) * 8;
    float4 v0 = *(const float4*)(dist + i8);
    float4 v1 = *(const float4*)(dist + i8 + 4);
    u16x8 o = { f2bf(exp2f(sc * v0.x)), f2bf(exp2f(sc * v0.y)),
                f2bf(exp2f(sc * v0.z)), f2bf(exp2f(sc * v0.w)),
                f2bf(exp2f(sc * v1.x)), f2bf(exp2f(sc * v1.y)),
                f2bf(exp2f(sc * v1.z)), f2bf(exp2f(sc * v1.w)) };
    *(u16x8*)(ea + i8) = o;
}

// ---------------------------------------------------------------------------
// Kernel C: pure bf16 GEMM, out = sigq * (num/den). (unchanged)
// ---------------------------------------------------------------------------
__global__ __launch_bounds__(256) void attn_kernel(
    const unsigned short* __restrict__ ea,
    const unsigned short* __restrict__ Pt,
    float* __restrict__ out)
{
    __shared__ __align__(128) unsigned short lds[2][2][128 * 64];

    const int bid = blockIdx.x;
    const int l = (bid & 7) * 64 + (bid >> 3);   // XCD-chunked, bijective (512%8==0)
    const int b = l >> 5;          // 0..15
    const int m = (l >> 2) & 7;
    const int n = l & 3;

    const int tid = threadIdx.x;
    const int w = tid >> 6, lane = tid & 63;
    const int wm = w >> 1, wn = w & 1;
    const int l15 = lane & 15, lhi = lane >> 4;
    const int lr = lane >> 3, cb = lane & 7;
    const int cbs = cb ^ lr;       // inverse-swizzled source colblock (XOR involution)

    const char* Abase = (const char*)(ea + ((size_t)b * NG + m * 128) * NG);
    const char* Bbase = (const char*)(Pt + ((size_t)b * 512 + n * 128) * NG);

    f32x4 acc[4][4];
    #pragma unroll
    for (int mi = 0; mi < 4; ++mi)
        #pragma unroll
        for (int ni = 0; ni < 4; ++ni)
            acc[mi][ni] = (f32x4){0.f, 0.f, 0.f, 0.f};

    auto STAGE = [&](int buf, int t) {
        #pragma unroll
        for (int i = 0; i < 4; ++i) {
            const int r = w * 32 + i * 8 + lr;          // tile row; r&7 == lr
            const size_t goff = (size_t)r * 2048 + t * 128 + cbs * 16;
            char* ldst = (char*)&lds[buf][0][0] + w * 4096 + i * 1024;
            gload16(Abase + goff, ldst);
            gload16(Bbase + goff, ldst + 16384);
        }
    };

    STAGE(0, 0);
    __syncthreads();

    int cur = 0;
    for (int t = 0; t < 16; ++t) {
        if (t < 15) STAGE(cur ^ 1, t + 1);
        const char* Ab = (const char*)&lds[cur][0][0];
        const char* Bb = (const char*)&lds[cur][1][0];
        #pragma unroll
        for (int kk = 0; kk < 2; ++kk) {
            const int bc = kk * 64 + lhi * 16;          // byte col within row
            bf16x8 af[4], bfr[4];
            #pragma unroll
            for (int mi = 0; mi < 4; ++mi) {
                const int tr = wm * 64 + mi * 16 + l15; // tr&7 == l15&7
                af[mi] = *(const bf16x8*)(Ab + ((tr * 128 + bc) ^ ((tr & 7) << 4)));
            }
            #pragma unroll
            for (int ni = 0; ni < 4; ++ni) {
                const int tr = wn * 64 + ni * 16 + l15;
                bfr[ni] = *(const bf16x8*)(Bb + ((tr * 128 + bc) ^ ((tr & 7) << 4)));
            }
            #pragma unroll
            for (int mi = 0; mi < 4; ++mi)
                #pragma unroll
                for (int ni = 0; ni < 4; ++ni)
                    acc[mi][ni] = __builtin_amdgcn_mfma_f32_16x16x32_bf16(
                        af[mi], bfr[ni], acc[mi][ni], 0, 0, 0);
        }
        __syncthreads();
        cur ^= 1;
    }

    const int parity = lane & 1;
    #pragma unroll
    for (int mi = 0; mi < 4; ++mi)
        #pragma unroll
        for (int ni = 0; ni < 4; ++ni)
            #pragma unroll
            for (int r = 0; r < 4; ++r) {
                const float own = acc[mi][ni][r];
                const float other = __shfl_xor(own, 1, 64);
                if (!parity) {
                    const int colg = n * 128 + wn * 64 + ni * 16 + l15;  // even
                    const int d = colg >> 1;
                    const int rowg = m * 128 + wm * 64 + mi * 16 + lhi * 4 + r;
                    const size_t idx = ((size_t)b * NG + rowg) * DM + d;
                    out[idx] = out[idx] * (own / (other + 1e-8f));  // out holds sigq
                }
            }
}

extern "C" void kernel_launch(void* const* d_in, const int* in_sizes, int n_in,
                              void* d_out, int out_size, void* d_ws, size_t ws_size,
                              hipStream_t stream) {
    const float* query = (const float*)d_in[0];
    const float* key_  = (const float*)d_in[1];
    const float* value = (const float*)d_in[2];
    const float* dist  = (const float*)d_in[3];
    const float* Wq = (const float*)d_in[4];
    const float* bq = (const float*)d_in[5];
    const float* Wk = (const float*)d_in[6];
    const float* bk = (const float*)d_in[7];
    const float* Wv = (const float*)d_in[8];
    const float* bv = (const float*)d_in[9];
    const float* alpha_raw = (const float*)d_in[10];
    float* out = (float*)d_out;

    // ws: Pt bf16 [32][512][1024] (32 MiB) | exp_A bf16 [HB][1024][1024] (32 MiB)
    //     | Wb bf16 [3][256][256] (384 KiB)
    unsigned short* Pt = (unsigned short*)d_ws;
    unsigned short* exp_buf =
        (unsigned short*)((char*)d_ws + (size_t)NBATCH * 512 * NG * sizeof(unsigned short));
    unsigned short* Wb = exp_buf + (size_t)HB * NG * NG;

    wpack_kernel<<<dim3(192), dim3(256), 0, stream>>>(Wq, Wk, Wv, Wb);

    // sigmoid(q) is staged in d_out; proj fully rewrites it every call.
    proj_kernel<<<dim3(2048), dim3(256), 0, stream>>>(
        query, key_, value, Wb, bq, bk, bv, out, Pt);

    for (int h = 0; h < 2; ++h) {
        exp_kernel<<<dim3(8192), dim3(256), 0, stream>>>(
            dist + (size_t)h * HB * NG * NG, exp_buf, alpha_raw);
        attn_kernel<<<dim3(512), dim3(256), 0, stream>>>(
            exp_buf, Pt + (size_t)h * HB * 512 * NG, out + (size_t)h * HB * NG * DM);
    }
}

// Round 7
// 194.478 us; speedup vs baseline: 1.3048x; 1.2845x over previous
//
#include <hip/hip_runtime.h>
#include <hip/hip_bf16.h>

#define NBATCH 32
#define NG 1024
#define DM 256
#define HB 16   // batches per attn pass

typedef short bf16x8 __attribute__((ext_vector_type(8)));
typedef float f32x4 __attribute__((ext_vector_type(4)));
typedef unsigned short u16x4 __attribute__((ext_vector_type(4)));
typedef unsigned short u16x8 __attribute__((ext_vector_type(8)));

static __device__ __forceinline__ unsigned short f2bf(float f) {
    __hip_bfloat16 h = __float2bfloat16(f);
    return *reinterpret_cast<unsigned short*>(&h);
}

// async global->LDS, 16B per lane. LDS dest wave-uniform (HW adds lane*16);
// global source is per-lane.
static __device__ __forceinline__ void gload16(const void* g, void* l) {
    __builtin_amdgcn_global_load_lds(
        (const __attribute__((address_space(1))) unsigned int*)g,
        (__attribute__((address_space(3))) unsigned int*)l, 16, 0, 0);
}

// ---------------------------------------------------------------------------
// Kernel W: pack Wq|Wk|Wv (f32 [e][d]) -> bf16 Wb[3][256][256]. L2-resident.
// ---------------------------------------------------------------------------
__global__ __launch_bounds__(256) void wpack_kernel(
    const float* __restrict__ Wq, const float* __restrict__ Wk,
    const float* __restrict__ Wv, unsigned short* __restrict__ Wb)
{
    const int i4 = (blockIdx.x * 256 + threadIdx.x) * 4;   // grid 192
    const int t = i4 >> 16;
    const int off = i4 & 65535;
    const float* src = (t == 0) ? Wq : (t == 1) ? Wk : Wv;
    float4 v = *(const float4*)(src + off);
    *(u16x4*)(Wb + i4) = (u16x4){ f2bf(v.x), f2bf(v.y), f2bf(v.z), f2bf(v.w) };
}

// ---------------------------------------------------------------------------
// Kernel X: f32 -> bf16 stream convert (8 elems/thread). grid 4096 per matrix.
// ---------------------------------------------------------------------------
__global__ __launch_bounds__(256) void conv_kernel(
    const float* __restrict__ src, unsigned short* __restrict__ dst)
{
    const size_t i8 = ((size_t)blockIdx.x * 256 + threadIdx.x) * 8;
    float4 a = *(const float4*)(src + i8);
    float4 b = *(const float4*)(src + i8 + 4);
    *(u16x8*)(dst + i8) = (u16x8){ f2bf(a.x), f2bf(a.y), f2bf(a.z), f2bf(a.w),
                                   f2bf(b.x), f2bf(b.y), f2bf(b.z), f2bf(b.w) };
}

// ---------------------------------------------------------------------------
// Kernel Q: sigq = sigmoid(Xq @ Wq^T + bq). Attn-clone structure:
// grid 512 = mt(256) x nt(2); tile 128x128, BK=64, 4 k-steps, dbuf LDS 64KB,
// gload_lds staging with XOR-swizzled per-lane source, swizzled ds_read_b128.
// ---------------------------------------------------------------------------
__global__ __launch_bounds__(256) void projq_kernel(
    const unsigned short* __restrict__ Xq,   // [32768][256] bf16
    const unsigned short* __restrict__ Wb,   // [256][256] bf16 (Wq)
    const float* __restrict__ bq,
    float* __restrict__ sigq)                // [32768][256] f32 (= d_out)
{
    __shared__ __align__(128) unsigned short lds[2][2][128 * 64];

    const int bid = blockIdx.x;
    const int mt = bid >> 1, nt = bid & 1;
    const int tid = threadIdx.x;
    const int w = tid >> 6, lane = tid & 63;
    const int wm = w >> 1, wn = w & 1;
    const int l15 = lane & 15, lhi = lane >> 4;
    const int lr = lane >> 3, sl = lane & 7;
    const int sp = sl ^ lr;                  // pre-swizzled source granule

    const char* Abase = (const char*)(Xq + (size_t)mt * 128 * 256);
    const char* Wbase = (const char*)(Wb + (size_t)nt * 128 * 256);

    f32x4 acc[4][4];
    #pragma unroll
    for (int mi = 0; mi < 4; ++mi)
        #pragma unroll
        for (int ni = 0; ni < 4; ++ni)
            acc[mi][ni] = (f32x4){0.f, 0.f, 0.f, 0.f};

    auto STAGE = [&](int buf, int t) {
        #pragma unroll
        for (int i = 0; i < 4; ++i) {
            const int r = w * 32 + i * 8 + lr;   // r&7 == lr
            gload16(Abase + (size_t)r * 512 + t * 128 + sp * 16,
                    (char*)&lds[buf][0][0] + w * 4096 + i * 1024);
            gload16(Wbase + (size_t)r * 512 + t * 128 + sp * 16,
                    (char*)&lds[buf][1][0] + w * 4096 + i * 1024);
        }
    };

    STAGE(0, 0);
    __syncthreads();

    int cur = 0;
    for (int t = 0; t < 4; ++t) {
        if (t < 3) STAGE(cur ^ 1, t + 1);
        const char* Ab = (const char*)&lds[cur][0][0];
        const char* Bb = (const char*)&lds[cur][1][0];
        #pragma unroll
        for (int kk = 0; kk < 2; ++kk) {
            bf16x8 af[4], bfr[4];
            #pragma unroll
            for (int mi = 0; mi < 4; ++mi) {
                const int tr = wm * 64 + mi * 16 + l15;
                af[mi] = *(const bf16x8*)(Ab + ((tr * 128 + kk * 64 + lhi * 16) ^ ((tr & 7) << 4)));
            }
            #pragma unroll
            for (int ni = 0; ni < 4; ++ni) {
                const int tr = wn * 64 + ni * 16 + l15;
                bfr[ni] = *(const bf16x8*)(Bb + ((tr * 128 + kk * 64 + lhi * 16) ^ ((tr & 7) << 4)));
            }
            #pragma unroll
            for (int mi = 0; mi < 4; ++mi)
                #pragma unroll
                for (int ni = 0; ni < 4; ++ni)
                    acc[mi][ni] = __builtin_amdgcn_mfma_f32_16x16x32_bf16(
                        af[mi], bfr[ni], acc[mi][ni], 0, 0, 0);
        }
        __syncthreads();
        cur ^= 1;
    }

    #pragma unroll
    for (int ni = 0; ni < 4; ++ni) {
        const int c = nt * 128 + wn * 64 + ni * 16 + l15;
        const float bqs = bq[c];
        #pragma unroll
        for (int mi = 0; mi < 4; ++mi)
            #pragma unroll
            for (int r = 0; r < 4; ++r) {
                const size_t R = (size_t)mt * 128 + wm * 64 + mi * 16 + lhi * 4 + r;
                const float qv = acc[mi][ni][r] + bqs;
                sigq[R * DM + c] = 1.0f / (1.0f + __expf(-qv));
            }
    }
}

// ---------------------------------------------------------------------------
// Kernel KV: k = Xk@Wk^T+bk, v = Xv@Wv^T+bv, Pt rows 2c/2c+1 = exp(k)*v/exp(k).
// Same attn-clone structure; each 128B LDS row = [k-slice 64B | v-slice 64B]
// (logical granules 0-3 = k, 4-7 = v), 8 k-steps of BK=32, 32 MFMA/step/wave.
// ---------------------------------------------------------------------------
__global__ __launch_bounds__(256) void projkv_kernel(
    const unsigned short* __restrict__ Xk,   // [32768][256] bf16
    const unsigned short* __restrict__ Xv,   // [32768][256] bf16
    const unsigned short* __restrict__ Wkb,  // [256][256] bf16
    const unsigned short* __restrict__ Wvb,  // [256][256] bf16
    const float* __restrict__ bk, const float* __restrict__ bv,
    unsigned short* __restrict__ Pt)
{
    __shared__ __align__(128) unsigned short lds[2][2][128 * 64];

    const int bid = blockIdx.x;
    const int mt = bid >> 1, nt = bid & 1;
    const int tid = threadIdx.x;
    const int w = tid >> 6, lane = tid & 63;
    const int wm = w >> 1, wn = w & 1;
    const int l15 = lane & 15, lhi = lane >> 4;
    const int lr = lane >> 3, sl = lane & 7;
    const int sp = sl ^ lr;                  // pre-swizzled logical granule
    const int g16 = (sp & 3) * 16;           // byte offset within 64B slice

    f32x4 kacc[4][4], vacc[4][4];
    #pragma unroll
    for (int mi = 0; mi < 4; ++mi)
        #pragma unroll
        for (int ni = 0; ni < 4; ++ni) {
            kacc[mi][ni] = (f32x4){0.f, 0.f, 0.f, 0.f};
            vacc[mi][ni] = (f32x4){0.f, 0.f, 0.f, 0.f};
        }

    auto STAGE = [&](int buf, int t) {
        #pragma unroll
        for (int i = 0; i < 4; ++i) {
            const int r = w * 32 + i * 8 + lr;   // r&7 == lr
            const char* asrc = (sp < 4 ? (const char*)Xk : (const char*)Xv)
                               + (size_t)(mt * 128 + r) * 512 + t * 64 + g16;
            gload16(asrc, (char*)&lds[buf][0][0] + w * 4096 + i * 1024);
            const char* wsrc = (sp < 4 ? (const char*)Wkb : (const char*)Wvb)
                               + (size_t)(nt * 128 + r) * 512 + t * 64 + g16;
            gload16(wsrc, (char*)&lds[buf][1][0] + w * 4096 + i * 1024);
        }
    };

    STAGE(0, 0);
    __syncthreads();

    int cur = 0;
    for (int t = 0; t < 8; ++t) {
        if (t < 7) STAGE(cur ^ 1, t + 1);
        const char* Ab = (const char*)&lds[cur][0][0];
        const char* Bb = (const char*)&lds[cur][1][0];
        bf16x8 kaf[4], vaf[4], kbf[4], vbf[4];
        #pragma unroll
        for (int mi = 0; mi < 4; ++mi) {
            const int tr = wm * 64 + mi * 16 + l15;
            const int sw = (tr & 7) << 4;
            kaf[mi] = *(const bf16x8*)(Ab + ((tr * 128 + lhi * 16) ^ sw));
            vaf[mi] = *(const bf16x8*)(Ab + ((tr * 128 + 64 + lhi * 16) ^ sw));
        }
        #pragma unroll
        for (int ni = 0; ni < 4; ++ni) {
            const int tr = wn * 64 + ni * 16 + l15;
            const int sw = (tr & 7) << 4;
            kbf[ni] = *(const bf16x8*)(Bb + ((tr * 128 + lhi * 16) ^ sw));
            vbf[ni] = *(const bf16x8*)(Bb + ((tr * 128 + 64 + lhi * 16) ^ sw));
        }
        #pragma unroll
        for (int mi = 0; mi < 4; ++mi)
            #pragma unroll
            for (int ni = 0; ni < 4; ++ni) {
                kacc[mi][ni] = __builtin_amdgcn_mfma_f32_16x16x32_bf16(
                    kaf[mi], kbf[ni], kacc[mi][ni], 0, 0, 0);
                vacc[mi][ni] = __builtin_amdgcn_mfma_f32_16x16x32_bf16(
                    vaf[mi], vbf[ni], vacc[mi][ni], 0, 0, 0);
            }
        __syncthreads();
        cur ^= 1;
    }

    // epilogue: Pt[b][2c][kidx] = exp(k)*v, Pt[b][2c+1][kidx] = exp(k)
    const int b = (mt * 128) >> 10;
    const int kb0 = (mt * 128) & 1023;
    #pragma unroll
    for (int ni = 0; ni < 4; ++ni) {
        const int c = nt * 128 + wn * 64 + ni * 16 + l15;
        const float bks = bk[c], bvs = bv[c];
        #pragma unroll
        for (int mi = 0; mi < 4; ++mi) {
            unsigned short p1[4], p2[4];
            #pragma unroll
            for (int r = 0; r < 4; ++r) {
                const float ek = __expf(kacc[mi][ni][r] + bks);
                const float vv = vacc[mi][ni][r] + bvs;
                p1[r] = f2bf(ek * vv);
                p2[r] = f2bf(ek);
            }
            const int kidx = kb0 + wm * 64 + mi * 16 + lhi * 4;
            *(u16x4*)&Pt[((size_t)b * 512 + 2 * c    ) * NG + kidx] =
                (u16x4){p1[0], p1[1], p1[2], p1[3]};
            *(u16x4*)&Pt[((size_t)b * 512 + 2 * c + 1) * NG + kidx] =
                (u16x4){p2[0], p2[1], p2[2], p2[3]};
        }
    }
}

// ---------------------------------------------------------------------------
// Kernel B: exp_A = bf16(exp2(sc * dist)) for HB batches. Memory-bound.
// ---------------------------------------------------------------------------
__global__ __launch_bounds__(256) void exp_kernel(
    const float* __restrict__ dist, unsigned short* __restrict__ ea,
    const float* __restrict__ alpha_raw)
{
    const float alpha = log1pf(__expf(alpha_raw[0])) + 1e-6f;
    const float sc = -alpha * 10.0f * 1.44269504088896f;
    const size_t i8 = ((size_t)blockIdx.x * 256 + threadIdx.x) * 8;
    float4 v0 = *(const float4*)(dist + i8);
    float4 v1 = *(const float4*)(dist + i8 + 4);
    u16x8 o = { f2bf(exp2f(sc * v0.x)), f2bf(exp2f(sc * v0.y)),
                f2bf(exp2f(sc * v0.z)), f2bf(exp2f(sc * v0.w)),
                f2bf(exp2f(sc * v1.x)), f2bf(exp2f(sc * v1.y)),
                f2bf(exp2f(sc * v1.z)), f2bf(exp2f(sc * v1.w)) };
    *(u16x8*)(ea + i8) = o;
}

// ---------------------------------------------------------------------------
// Kernel C: pure bf16 GEMM, out = sigq * (num/den). (unchanged, proven)
// ---------------------------------------------------------------------------
__global__ __launch_bounds__(256) void attn_kernel(
    const unsigned short* __restrict__ ea,
    const unsigned short* __restrict__ Pt,
    float* __restrict__ out)
{
    __shared__ __align__(128) unsigned short lds[2][2][128 * 64];

    const int bid = blockIdx.x;
    const int l = (bid & 7) * 64 + (bid >> 3);   // XCD-chunked, bijective
    const int b = l >> 5;
    const int m = (l >> 2) & 7;
    const int n = l & 3;

    const int tid = threadIdx.x;
    const int w = tid >> 6, lane = tid & 63;
    const int wm = w >> 1, wn = w & 1;
    const int l15 = lane & 15, lhi = lane >> 4;
    const int lr = lane >> 3, cb = lane & 7;
    const int cbs = cb ^ lr;

    const char* Abase = (const char*)(ea + ((size_t)b * NG + m * 128) * NG);
    const char* Bbase = (const char*)(Pt + ((size_t)b * 512 + n * 128) * NG);

    f32x4 acc[4][4];
    #pragma unroll
    for (int mi = 0; mi < 4; ++mi)
        #pragma unroll
        for (int ni = 0; ni < 4; ++ni)
            acc[mi][ni] = (f32x4){0.f, 0.f, 0.f, 0.f};

    auto STAGE = [&](int buf, int t) {
        #pragma unroll
        for (int i = 0; i < 4; ++i) {
            const int r = w * 32 + i * 8 + lr;
            const size_t goff = (size_t)r * 2048 + t * 128 + cbs * 16;
            char* ldst = (char*)&lds[buf][0][0] + w * 4096 + i * 1024;
            gload16(Abase + goff, ldst);
            gload16(Bbase + goff, ldst + 16384);
        }
    };

    STAGE(0, 0);
    __syncthreads();

    int cur = 0;
    for (int t = 0; t < 16; ++t) {
        if (t < 15) STAGE(cur ^ 1, t + 1);
        const char* Ab = (const char*)&lds[cur][0][0];
        const char* Bb = (const char*)&lds[cur][1][0];
        #pragma unroll
        for (int kk = 0; kk < 2; ++kk) {
            const int bc = kk * 64 + lhi * 16;
            bf16x8 af[4], bfr[4];
            #pragma unroll
            for (int mi = 0; mi < 4; ++mi) {
                const int tr = wm * 64 + mi * 16 + l15;
                af[mi] = *(const bf16x8*)(Ab + ((tr * 128 + bc) ^ ((tr & 7) << 4)));
            }
            #pragma unroll
            for (int ni = 0; ni < 4; ++ni) {
                const int tr = wn * 64 + ni * 16 + l15;
                bfr[ni] = *(const bf16x8*)(Bb + ((tr * 128 + bc) ^ ((tr & 7) << 4)));
            }
            #pragma unroll
            for (int mi = 0; mi < 4; ++mi)
                #pragma unroll
                for (int ni = 0; ni < 4; ++ni)
                    acc[mi][ni] = __builtin_amdgcn_mfma_f32_16x16x32_bf16(
                        af[mi], bfr[ni], acc[mi][ni], 0, 0, 0);
        }
        __syncthreads();
        cur ^= 1;
    }

    const int parity = lane & 1;
    #pragma unroll
    for (int mi = 0; mi < 4; ++mi)
        #pragma unroll
        for (int ni = 0; ni < 4; ++ni)
            #pragma unroll
            for (int r = 0; r < 4; ++r) {
                const float own = acc[mi][ni][r];
                const float other = __shfl_xor(own, 1, 64);
                if (!parity) {
                    const int colg = n * 128 + wn * 64 + ni * 16 + l15;
                    const int d = colg >> 1;
                    const int rowg = m * 128 + wm * 64 + mi * 16 + lhi * 4 + r;
                    const size_t idx = ((size_t)b * NG + rowg) * DM + d;
                    out[idx] = out[idx] * (own / (other + 1e-8f));
                }
            }
}

extern "C" void kernel_launch(void* const* d_in, const int* in_sizes, int n_in,
                              void* d_out, int out_size, void* d_ws, size_t ws_size,
                              hipStream_t stream) {
    const float* query = (const float*)d_in[0];
    const float* key_  = (const float*)d_in[1];
    const float* value = (const float*)d_in[2];
    const float* dist  = (const float*)d_in[3];
    const float* Wq = (const float*)d_in[4];
    const float* bq = (const float*)d_in[5];
    const float* Wk = (const float*)d_in[6];
    const float* bk = (const float*)d_in[7];
    const float* Wv = (const float*)d_in[8];
    const float* bv = (const float*)d_in[9];
    const float* alpha_raw = (const float*)d_in[10];
    float* out = (float*)d_out;

    // ws layout (proven 67.5 MB): Pt 32M | exp region 32M (reused for Xb) | Wb 384K
    unsigned short* Pt = (unsigned short*)d_ws;
    unsigned short* exp_buf =
        (unsigned short*)((char*)d_ws + (size_t)NBATCH * 512 * NG * sizeof(unsigned short));
    unsigned short* Wb = exp_buf + (size_t)HB * NG * NG;

    const size_t XN = (size_t)NBATCH * NG * DM;   // 8.39M elems per matrix

    wpack_kernel<<<dim3(192), dim3(256), 0, stream>>>(Wq, Wk, Wv, Wb);

    // --- q path: conv query -> exp region, GEMM -> sigq (in d_out) ---
    conv_kernel<<<dim3(4096), dim3(256), 0, stream>>>(query, exp_buf);
    projq_kernel<<<dim3(512), dim3(256), 0, stream>>>(exp_buf, Wb, bq, out);

    // --- kv path: conv key/value -> exp region, fused GEMM -> Pt ---
    unsigned short* Xk = exp_buf;
    unsigned short* Xv = exp_buf + XN;
    conv_kernel<<<dim3(4096), dim3(256), 0, stream>>>(key_, Xk);
    conv_kernel<<<dim3(4096), dim3(256), 0, stream>>>(value, Xv);
    projkv_kernel<<<dim3(512), dim3(256), 0, stream>>>(
        Xk, Xv, Wb + 65536, Wb + 131072, bk, bv, Pt);

    // --- main attention GEMM, two half-batches ---
    for (int h = 0; h < 2; ++h) {
        exp_kernel<<<dim3(8192), dim3(256), 0, stream>>>(
            dist + (size_t)h * HB * NG * NG, exp_buf, alpha_raw);
        attn_kernel<<<dim3(512), dim3(256), 0, stream>>>(
            exp_buf, Pt + (size_t)h * HB * 512 * NG, out + (size_t)h * HB * NG * DM);
    }
}